// Round 1
// baseline (27410.159 us; speedup 1.0000x reference)
//
#include <hip/hip_runtime.h>
#include <hip/hip_fp16.h>

#define HID   512
#define EMB   256
#define VOCAB 64
#define NL    2
#define BS    64
#define SLEN  128
#define LLEN  1024
#define G4    2048
#define NCH   4

// ---------------------------------------------------------------------------
// embedding gather: xemb[t][b][e] = emb[y[b][t]][e]
__global__ __launch_bounds__(256)
void k_embed(const int* __restrict__ y, const float* __restrict__ emb,
             float* __restrict__ xemb)
{
    int i = blockIdx.x * 256 + threadIdx.x;      // 0 .. S*B*EMB-1
    int ts = i >> 14;            // /(BS*EMB)
    int r  = i & 16383;
    int b  = r >> 8;
    int e  = r & 255;
    int yv = y[b * SLEN + ts];
    xemb[i] = emb[yv * EMB + e];
}

// cast encoder to f16
__global__ __launch_bounds__(256)
void k_cast(const float* __restrict__ src, __half* __restrict__ dst, int n4)
{
    int i = blockIdx.x * 256 + threadIdx.x;
    int stride = gridDim.x * 256;
    for (; i < n4; i += stride) {
        float4 v = reinterpret_cast<const float4*>(src)[i];
        __half2 lo = __floats2half2_rn(v.x, v.y);
        __half2 hi = __floats2half2_rn(v.z, v.w);
        reinterpret_cast<__half2*>(dst)[2 * i]     = lo;
        reinterpret_cast<__half2*>(dst)[2 * i + 1] = hi;
    }
}

// P[i][j] = sum_h Whw[h][i]*Wsw[h][j];  p0[i] = sum_h Whw[h][i]*Wsb[h]
__global__ __launch_bounds__(256)
void k_pmat(const float* __restrict__ Whw, const float* __restrict__ Wsw,
            const float* __restrict__ Wsb, float* __restrict__ P,
            float* __restrict__ p0)
{
    const int i = blockIdx.x;        // 0..511
    const int t = threadIdx.x;       // j, j+256
    float a0 = 0.f, a1 = 0.f, ap = 0.f;
    for (int h = 0; h < HID; ++h) {
        float whi = Whw[h * HID + i];
        a0 += whi * Wsw[h * HID + t];
        a1 += whi * Wsw[h * HID + t + 256];
        ap += whi * Wsb[h];
    }
    P[i * HID + t]       = a0;
    P[i * HID + t + 256] = a1;
    if (t == 0) p0[i] = ap;
}

// ---------------------------------------------------------------------------
// fused LSTM cell: gates = [A0|A1] @ Wih^T + A2 @ Whh^T + bih + bhh
// grid 256 (h-pairs), block 256.  lane=b, 4 k-split waves, acc[2h][4g].
__global__ __launch_bounds__(256)
void k_cell(const float* __restrict__ A0, int K0,
            const float* __restrict__ A1, int K1,
            const float* __restrict__ A2,
            const float* __restrict__ Wih, int ldWih,
            const float* __restrict__ Whh,
            const float* __restrict__ bih, const float* __restrict__ bhh,
            float* __restrict__ c_io,
            float* __restrict__ h_out)
{
    __shared__ __align__(16) float As[64 * 130];
    __shared__ float red[4][8][66];
    const int t    = threadIdx.x;
    const int wv   = __builtin_amdgcn_readfirstlane(t >> 6);
    const int lane = t & 63;
    const int h0g  = blockIdx.x * 2;

    float acc[2][4];
#pragma unroll
    for (int hl = 0; hl < 2; ++hl)
#pragma unroll
        for (int g = 0; g < 4; ++g) acc[hl][g] = 0.f;

    for (int ph = 0; ph < 3; ++ph) {
        const float* A; int K; const float* W; int ldW; int co;
        if (ph == 0)      { A = A0; K = K0;  W = Wih; ldW = ldWih; co = 0;  }
        else if (ph == 1) { A = A1; K = K1;  W = Wih; ldW = ldWih; co = K0; }
        else              { A = A2; K = HID; W = Whh; ldW = HID;   co = 0;  }
        if (K == 0) continue;
        for (int k0 = 0; k0 < K; k0 += 128) {
            __syncthreads();
#pragma unroll
            for (int p = 0; p < 8; ++p) {           // stage 64x128 f32
                int f = p * 256 + t;
                int b = f >> 5;
                int q = f & 31;
                float4 d = *reinterpret_cast<const float4*>(A + (size_t)b * K + k0 + q * 4);
                float* dst = &As[b * 130 + q * 4];
                dst[0] = d.x; dst[1] = d.y; dst[2] = d.z; dst[3] = d.w;
            }
            __syncthreads();
            const int kw = wv * 32;
#pragma unroll
            for (int kk = 0; kk < 32; kk += 2) {
                float2 a = *reinterpret_cast<const float2*>(&As[lane * 130 + kw + kk]);
#pragma unroll
                for (int hl = 0; hl < 2; ++hl)
#pragma unroll
                    for (int g = 0; g < 4; ++g) {
                        const float* wp = W + (size_t)(g * HID + h0g + hl) * ldW + co + k0 + kw + kk;
                        acc[hl][g] += a.x * wp[0] + a.y * wp[1];
                    }
            }
        }
    }
    __syncthreads();
#pragma unroll
    for (int hl = 0; hl < 2; ++hl)
#pragma unroll
        for (int g = 0; g < 4; ++g)
            red[wv][hl * 4 + g][lane] = acc[hl][g];
    __syncthreads();
    if (t < 128) {
        const int b  = t & 63;
        const int hl = t >> 6;
        float gs[4];
#pragma unroll
        for (int g = 0; g < 4; ++g) {
            const int row = g * HID + h0g + hl;
            gs[g] = red[0][hl * 4 + g][b] + red[1][hl * 4 + g][b]
                  + red[2][hl * 4 + g][b] + red[3][hl * 4 + g][b]
                  + bih[row] + bhh[row];
        }
        const float ig = 1.f / (1.f + __expf(-gs[0]));
        const float fg = 1.f / (1.f + __expf(-gs[1]));
        const float gg = tanhf(gs[2]);
        const float og = 1.f / (1.f + __expf(-gs[3]));
        const int idx = b * HID + h0g + hl;
        const float c2 = fg * c_io[idx] + ig * gg;
        c_io[idx]  = c2;
        h_out[idx] = og * tanhf(c2);
    }
}

// ---------------------------------------------------------------------------
// small linear: out[b][i] = act(bias[i] + sum_k W[i][k]*A0[b][k] (+ A1 phase))
// grid 128 (4 rows each), block 256
__global__ __launch_bounds__(256)
void k_lin(const float* __restrict__ A0, int K0,
           const float* __restrict__ A1, int K1,
           const float* __restrict__ W, int ldW,
           const float* __restrict__ bias,
           float* __restrict__ out, int doRelu)
{
    __shared__ __align__(16) float As[64 * 130];
    __shared__ float red[4][4][66];
    const int t    = threadIdx.x;
    const int wv   = __builtin_amdgcn_readfirstlane(t >> 6);
    const int lane = t & 63;
    const int i0   = blockIdx.x * 4;
    float acc[4] = {0.f, 0.f, 0.f, 0.f};

    for (int ph = 0; ph < 2; ++ph) {
        const float* A = ph ? A1 : A0;
        const int K    = ph ? K1 : K0;
        const int co   = ph ? K0 : 0;
        if (K == 0) continue;
        for (int k0 = 0; k0 < K; k0 += 128) {
            __syncthreads();
#pragma unroll
            for (int p = 0; p < 8; ++p) {
                int f = p * 256 + t;
                int b = f >> 5;
                int q = f & 31;
                float4 d = *reinterpret_cast<const float4*>(A + (size_t)b * K + k0 + q * 4);
                float* dst = &As[b * 130 + q * 4];
                dst[0] = d.x; dst[1] = d.y; dst[2] = d.z; dst[3] = d.w;
            }
            __syncthreads();
            const int kw = wv * 32;
#pragma unroll
            for (int kk = 0; kk < 32; kk += 2) {
                float2 a = *reinterpret_cast<const float2*>(&As[lane * 130 + kw + kk]);
#pragma unroll
                for (int r = 0; r < 4; ++r) {
                    const float* wp = W + (size_t)(i0 + r) * ldW + co + k0 + kw + kk;
                    acc[r] += a.x * wp[0] + a.y * wp[1];
                }
            }
        }
    }
    __syncthreads();
#pragma unroll
    for (int r = 0; r < 4; ++r) red[wv][r][lane] = acc[r];
    __syncthreads();
    {
        const int b = t & 63;
        const int r = t >> 6;
        float s = red[0][r][b] + red[1][r][b] + red[2][r][b] + red[3][r][b] + bias[i0 + r];
        if (doRelu) s = fmaxf(s, 0.f);
        out[b * HID + i0 + r] = s;
    }
}

// ---------------------------------------------------------------------------
// attention partial pass (online softmax + weighted encoder sum)
// grid 256 = 64 b x 4 chunks of 256 l.  Partials (m,s,v[512]) per wg.
template<int USE16>
__global__ __launch_bounds__(256)
void k_attn(const float* __restrict__ uvec,
            const __half* __restrict__ enc16,
            const float* __restrict__ encf,
            float* __restrict__ pm, float* __restrict__ ps,
            float* __restrict__ pv)
{
    constexpr int ROWS = USE16 ? 32 : 16;
    constexpr int NBLK = 256 / ROWS;
    constexpr int SEGS = 256 / ROWS;
    constexpr int UPS  = 256 / SEGS;      // half2-units per seg
    constexpr int LD16 = 261;             // u32 per row (f16 path)
    constexpr int LDF  = 522;             // f32 per row (f32 path)

    __shared__ __align__(16) float u_s[HID];
    __shared__ float w_s[ROWS];
    __shared__ float accs[SEGS][ROWS + 2];
    __shared__ float msh[4];
    __shared__ __align__(16) unsigned int encbuf[USE16 ? (ROWS * LD16) : (ROWS * LDF)];

    const int t  = threadIdx.x;
    const int b  = blockIdx.x >> 2;
    const int ch = blockIdx.x & 3;

    u_s[t]       = uvec[b * HID + t];
    u_s[t + 256] = uvec[b * HID + t + 256];
    if (t == 0) { msh[0] = -3.0e38f; msh[1] = 0.f; msh[2] = 0.f; }
    float vx = 0.f, vy = 0.f;
    __syncthreads();

    for (int blk = 0; blk < NBLK; ++blk) {
        const int l0 = ch * 256 + blk * ROWS;
        if constexpr (USE16) {
            const uint4* src = reinterpret_cast<const uint4*>(enc16 + ((size_t)b * LLEN + l0) * HID);
#pragma unroll
            for (int p = 0; p < ROWS * 64 / 256; ++p) {
                int f = p * 256 + t;
                int l = f >> 6, q = f & 63;
                uint4 d = src[l * 64 + q];
                unsigned int* dst = &encbuf[l * LD16 + q * 4];
                dst[0] = d.x; dst[1] = d.y; dst[2] = d.z; dst[3] = d.w;
            }
        } else {
            const float4* src = reinterpret_cast<const float4*>(encf + ((size_t)b * LLEN + l0) * HID);
            float* es = reinterpret_cast<float*>(encbuf);
#pragma unroll
            for (int p = 0; p < ROWS * 128 / 256; ++p) {
                int f = p * 256 + t;
                int l = f >> 7, q = f & 127;
                float4 d = src[l * 128 + q];
                float* dst = &es[l * LDF + q * 4];
                dst[0] = d.x; dst[1] = d.y; dst[2] = d.z; dst[3] = d.w;
            }
        }
        __syncthreads();
        {   // pass-e: scores
            const int l   = t % ROWS;
            const int seg = t / ROWS;
            float acc = 0.f;
            if constexpr (USE16) {
                const unsigned int* er = &encbuf[l * LD16];
#pragma unroll
                for (int uu = 0; uu < UPS; ++uu) {
                    const int u = seg * UPS + uu;
                    float2 f2 = __half22float2(*reinterpret_cast<const __half2*>(&er[u]));
                    float2 uv = *reinterpret_cast<const float2*>(&u_s[2 * u]);
                    acc += uv.x * f2.x + uv.y * f2.y;
                }
            } else {
                const float* er = reinterpret_cast<const float*>(encbuf) + l * LDF;
#pragma unroll
                for (int uu = 0; uu < UPS; ++uu) {
                    const int u = seg * UPS + uu;
                    float2 f2 = *reinterpret_cast<const float2*>(&er[2 * u]);
                    float2 uv = *reinterpret_cast<const float2*>(&u_s[2 * u]);
                    acc += uv.x * f2.x + uv.y * f2.y;
                }
            }
            accs[seg][l] = acc;
        }
        __syncthreads();
        if (t < ROWS) {   // online softmax bookkeeping (wave 0)
            float e = 0.f;
#pragma unroll
            for (int s2 = 0; s2 < SEGS; ++s2) e += accs[s2][t];
            float bm = e;
#pragma unroll
            for (int off = ROWS / 2; off > 0; off >>= 1) bm = fmaxf(bm, __shfl_xor(bm, off));
            const float m_old = msh[0];
            const float m_new = fmaxf(m_old, bm);
            const float wl = __expf(e - m_new);
            float sw = wl;
#pragma unroll
            for (int off = ROWS / 2; off > 0; off >>= 1) sw += __shfl_xor(sw, off);
            w_s[t] = wl;
            if (t == 0) {
                const float sc = __expf(m_old - m_new);
                msh[2] = sc;
                msh[1] = msh[1] * sc + sw;
                msh[0] = m_new;
            }
        }
        __syncthreads();
        {   // pass-v: weighted accumulate, k-pair per thread
            const float sc = msh[2];
            vx *= sc; vy *= sc;
            if constexpr (USE16) {
#pragma unroll
                for (int l = 0; l < ROWS; ++l) {
                    float wl = w_s[l];
                    float2 f2 = __half22float2(*reinterpret_cast<const __half2*>(&encbuf[l * LD16 + t]));
                    vx += wl * f2.x; vy += wl * f2.y;
                }
            } else {
                const float* ef = reinterpret_cast<const float*>(encbuf);
#pragma unroll
                for (int l = 0; l < ROWS; ++l) {
                    float wl = w_s[l];
                    float2 f2 = *reinterpret_cast<const float2*>(&ef[l * LDF + 2 * t]);
                    vx += wl * f2.x; vy += wl * f2.y;
                }
            }
        }
        __syncthreads();
    }
    const int pc = b * NCH + ch;
    if (t == 0) { pm[pc] = msh[0]; ps[pc] = msh[1]; }
    pv[(size_t)pc * HID + 2 * t]     = vx;
    pv[(size_t)pc * HID + 2 * t + 1] = vy;
}

// combine chunk partials -> chat[b][j]
__global__ __launch_bounds__(256)
void k_combine(const float* __restrict__ pm, const float* __restrict__ ps,
               const float* __restrict__ pv, float* __restrict__ chat)
{
    int i = blockIdx.x * 256 + threadIdx.x;   // 0..32767
    int b = i >> 9;
    int j = i & 511;
    float m0 = pm[b * 4], m1 = pm[b * 4 + 1], m2 = pm[b * 4 + 2], m3 = pm[b * 4 + 3];
    float M  = fmaxf(fmaxf(m0, m1), fmaxf(m2, m3));
    float e0 = __expf(m0 - M), e1 = __expf(m1 - M), e2 = __expf(m2 - M), e3 = __expf(m3 - M);
    float den = e0 * ps[b * 4] + e1 * ps[b * 4 + 1] + e2 * ps[b * 4 + 2] + e3 * ps[b * 4 + 3];
    float num = e0 * pv[(size_t)(b * 4 + 0) * HID + j] + e1 * pv[(size_t)(b * 4 + 1) * HID + j]
              + e2 * pv[(size_t)(b * 4 + 2) * HID + j] + e3 * pv[(size_t)(b * 4 + 3) * HID + j];
    chat[i] = num / den;
}

// logits: out[b*S+t][v] = b2[v] + sum_h W2[v][h]*hidden[b][h]
__global__ __launch_bounds__(256)
void k_mlp2(const float* __restrict__ hidden, const float* __restrict__ W2,
            const float* __restrict__ b2, float* __restrict__ out, int tstep)
{
    const int b    = blockIdx.x;
    const int t    = threadIdx.x;
    const int wv   = t >> 6;
    const int lane = t & 63;
    float hreg[8];
    const float* hp = hidden + b * HID + lane * 8;
#pragma unroll
    for (int i = 0; i < 8; ++i) hreg[i] = hp[i];
    for (int v = wv * 16; v < wv * 16 + 16; ++v) {
        const float* wp = W2 + v * HID + lane * 8;
        float s = 0.f;
#pragma unroll
        for (int i = 0; i < 8; ++i) s += hreg[i] * wp[i];
#pragma unroll
        for (int off = 32; off > 0; off >>= 1) s += __shfl_xor(s, off);
        if (lane == 0) out[((size_t)b * SLEN + tstep) * VOCAB + v] = s + b2[v];
    }
}

// ---------------------------------------------------------------------------
extern "C" void kernel_launch(void* const* d_in, const int* in_sizes, int n_in,
                              void* d_out, int out_size, void* d_ws, size_t ws_size,
                              hipStream_t stream)
{
    const int*   y    = (const int*)  d_in[0];
    const float* enc  = (const float*)d_in[1];
    const float* emb  = (const float*)d_in[2];
    const float* aWih = (const float*)d_in[3];
    const float* aWhh = (const float*)d_in[4];
    const float* abih = (const float*)d_in[5];
    const float* abhh = (const float*)d_in[6];
    const float* rWih = (const float*)d_in[7];
    const float* rWhh = (const float*)d_in[8];
    const float* rbih = (const float*)d_in[9];
    const float* rbhh = (const float*)d_in[10];
    const float* Wsw  = (const float*)d_in[11];
    const float* Wsb  = (const float*)d_in[12];
    const float* Whw  = (const float*)d_in[13];
    const float* Whb  = (const float*)d_in[14];
    const float* W1   = (const float*)d_in[15];
    const float* b1   = (const float*)d_in[16];
    const float* W2   = (const float*)d_in[17];
    const float* b2   = (const float*)d_in[18];
    float* out = (float*)d_out;

    float* p = (float*)d_ws;
    float* xemb = p;  p += (size_t)SLEN * BS * EMB;
    float* h0   = p;  p += 2 * BS * HID;
    float* c0   = p;  p += BS * HID;
    float* hs   = p;  p += 2 * NL * BS * HID;
    float* cs   = p;  p += NL * BS * HID;
    float* ctxb = p;  p += BS * HID;
    float* ub   = p;  p += BS * HID;
    float* chat = p;  p += BS * HID;
    float* Pm   = p;  p += HID * HID;
    float* p0v  = p;  p += HID;
    float* pmb  = p;  p += BS * NCH;
    float* psb  = p;  p += BS * NCH;
    float* pvb  = p;  p += (size_t)BS * NCH * HID;
    float* hid  = p;  p += BS * HID;
    __half* enc16 = (__half*)p;
    size_t need = (size_t)((char*)p - (char*)d_ws) + sizeof(__half) * (size_t)BS * LLEN * HID;
    const bool use16 = (ws_size >= need);

    // zero recurrent state (h0 both halves, c0, hs both halves, cs, ctx)
    size_t zeroFloats = (size_t)2 * BS * HID + BS * HID + 2 * NL * BS * HID + NL * BS * HID + BS * HID;
    hipMemsetAsync(h0, 0, zeroFloats * sizeof(float), stream);

    k_embed<<<(SLEN * BS * EMB) / 256, 256, 0, stream>>>(y, emb, xemb);
    if (use16) k_cast<<<4096, 256, 0, stream>>>(enc, enc16, (BS * LLEN * HID) / 4);
    k_pmat<<<HID, 256, 0, stream>>>(Whw, Wsw, Wsb, Pm, p0v);

    for (int t = 0; t < SLEN; ++t) {
        const int par = t & 1;
        float* h0r = h0 + par * BS * HID;
        float* h0w = h0 + (par ^ 1) * BS * HID;
        float* hsr = hs + par * NL * BS * HID;
        float* hsw = hs + (par ^ 1) * NL * BS * HID;

        // attention-input LSTM cell: x=[xemb_t | ctx], h=h0
        k_cell<<<256, 256, 0, stream>>>(xemb + (size_t)t * BS * EMB, EMB,
                                        ctxb, HID, h0r,
                                        aWih, EMB + HID, aWhh, abih, abhh,
                                        c0, h0w);
        // rnn layer 0
        k_cell<<<256, 256, 0, stream>>>(h0w, HID, nullptr, 0, hsr,
                                        rWih, HID, rWhh, rbih, rbhh,
                                        cs, hsw);
        // rnn layer 1
        k_cell<<<256, 256, 0, stream>>>(hsw, HID, nullptr, 0, hsr + BS * HID,
                                        rWih + (size_t)G4 * HID, HID,
                                        rWhh + (size_t)G4 * HID,
                                        rbih + G4, rbhh + G4,
                                        cs + BS * HID, hsw + BS * HID);
        float* prev = hsw + BS * HID;

        // u = P*prev + p0   (folded Wh^T * (Ws*prev + Ws_b))
        k_lin<<<128, 256, 0, stream>>>(prev, HID, nullptr, 0, Pm, HID, p0v, ub, 0);

        if (use16) k_attn<1><<<256, 256, 0, stream>>>(ub, enc16, nullptr, pmb, psb, pvb);
        else       k_attn<0><<<256, 256, 0, stream>>>(ub, nullptr, enc,   pmb, psb, pvb);

        k_combine<<<128, 256, 0, stream>>>(pmb, psb, pvb, chat);

        // ctx = Wh*chat + Wh_b
        k_lin<<<128, 256, 0, stream>>>(chat, HID, nullptr, 0, Whw, HID, Whb, ctxb, 0);
        // hidden = relu(W1 [prev|ctx] + b1)
        k_lin<<<128, 256, 0, stream>>>(prev, HID, ctxb, HID, W1, 2 * HID, b1, hid, 1);
        // logits
        k_mlp2<<<BS, 256, 0, stream>>>(hid, W2, b2, out, t);
    }
}